// Round 3
// baseline (181.692 us; speedup 1.0000x reference)
//
#include <hip/hip_runtime.h>
#include <math.h>

// NoisyTopkRouter, all-f32.
// x[ntok,384] @ {w_route,w_noise}[8,384]^T -> 16 logits/token,
// noisy = logit + noise*softplus(noise_logit), top-2 of 8, sparse softmax.
// Output: [ntok*8 probs f32 | ntok*2 indices-as-f32].
//
// R2: LDS-traffic was the bottleneck (24.6 KB LDS read per token ≈ 31 µs total).
// Now each thread carries 4 tokens per weight fragment (LDS /4 ≈ 8 µs < HBM 16 µs).
// Wave = 8 token-groups × 8 d-slices; group tg owns tokens tok0..tok0+3.
// After xor-reduce over slices, lanes c=0..3 each finish token tok0+c.

constexpr int D = 384;

__global__ __launch_bounds__(256) void noisy_topk_router_f32(
    const float* __restrict__ x,        // [ntok,384]
    const float* __restrict__ noise,    // [ntok,8]
    const float* __restrict__ w_route,  // [8,384]
    const float* __restrict__ b_route,  // [8]
    const float* __restrict__ w_noise,  // [8,384]
    const float* __restrict__ b_noise,  // [8]
    float* __restrict__ out,            // [ntok*8 | ntok*2]
    int ntok)
{
    __shared__ float w_lds[16 * D];   // rows: e=0..7 route, e=8..15 noise (contiguous)
    __shared__ float bias[16];

    const int tid = threadIdx.x;

    // stage weights: 2 x 3072 floats = 2 x 768 float4; 256 threads x 3 each
#pragma unroll
    for (int r = 0; r < 3; ++r) {
        int i = (tid + 256 * r) * 4;                       // < 3072
        *(float4*)(w_lds + i)            = *(const float4*)(w_route + i);
        *(float4*)(w_lds + 3072 + i)     = *(const float4*)(w_noise + i);
    }
    if (tid < 8)       bias[tid] = b_route[tid];
    else if (tid < 16) bias[tid] = b_noise[tid - 8];
    __syncthreads();

    const int wave = tid >> 6;
    const int lane = tid & 63;
    const int tg   = lane >> 3;       // token-group 0..7
    const int c    = lane & 7;        // d-slice 0..7 (48 d each)
    // wave covers 32 tokens; block covers 128
    const int tok0 = blockIdx.x * 128 + wave * 32 + tg * 4;

    float acc[4][16];
#pragma unroll
    for (int t = 0; t < 4; ++t)
#pragma unroll
        for (int e = 0; e < 16; ++e) acc[t][e] = 0.f;

    const float* xbase = x + (size_t)tok0 * D + c * 4;
#pragma unroll 2
    for (int j = 0; j < 12; ++j) {
        const int dbase = j * 32;
        float4 xv0 = *(const float4*)(xbase + dbase);
        float4 xv1 = *(const float4*)(xbase + D + dbase);
        float4 xv2 = *(const float4*)(xbase + 2 * D + dbase);
        float4 xv3 = *(const float4*)(xbase + 3 * D + dbase);
#pragma unroll
        for (int e = 0; e < 16; ++e) {
            float4 wv = *(const float4*)(w_lds + e * D + dbase + c * 4);
            acc[0][e] += xv0.x * wv.x + xv0.y * wv.y + xv0.z * wv.z + xv0.w * wv.w;
            acc[1][e] += xv1.x * wv.x + xv1.y * wv.y + xv1.z * wv.z + xv1.w * wv.w;
            acc[2][e] += xv2.x * wv.x + xv2.y * wv.y + xv2.z * wv.z + xv2.w * wv.w;
            acc[3][e] += xv3.x * wv.x + xv3.y * wv.y + xv3.z * wv.z + xv3.w * wv.w;
        }
    }

    // reduce over the 8 d-slices; afterwards every lane holds full sums
#pragma unroll
    for (int t = 0; t < 4; ++t)
#pragma unroll
        for (int e = 0; e < 16; ++e) {
            acc[t][e] += __shfl_xor(acc[t][e], 1);
            acc[t][e] += __shfl_xor(acc[t][e], 2);
            acc[t][e] += __shfl_xor(acc[t][e], 4);
        }

    if (c < 4) {
        const int token = tok0 + c;     // lane c finishes token tok0+c, using acc[c]
        float4 n0 = *(const float4*)(noise + (size_t)token * 8);
        float4 n1 = *(const float4*)(noise + (size_t)token * 8 + 4);
        float nz[8] = {n0.x, n0.y, n0.z, n0.w, n1.x, n1.y, n1.z, n1.w};

        float noisy[8];
#pragma unroll
        for (int e = 0; e < 8; ++e) {
            float lg = acc[c][e] + bias[e];
            float nl = acc[c][8 + e] + bias[8 + e];
            // stable softplus: max(z,0) + log1p(exp(-|z|))
            float sp = fmaxf(nl, 0.f) + log1pf(expf(-fabsf(nl)));
            noisy[e] = lg + nz[e] * sp;
        }

        // top-2, jax.lax.top_k tie-break: earliest index wins ties
        float v0 = noisy[0]; int i0 = 0;
#pragma unroll
        for (int e = 1; e < 8; ++e)
            if (noisy[e] > v0) { v0 = noisy[e]; i0 = e; }
        float v1 = -INFINITY; int i1 = 0;
#pragma unroll
        for (int e = 0; e < 8; ++e)
            if (e != i0 && noisy[e] > v1) { v1 = noisy[e]; i1 = e; }

        // 2-way softmax (other experts exactly 0)
        float ex  = expf(v1 - v0);       // v1 <= v0
        float inv = 1.f / (1.f + ex);
        float p0  = inv;
        float p1  = ex * inv;

        float pr[8];
#pragma unroll
        for (int e = 0; e < 8; ++e)
            pr[e] = (e == i0) ? p0 : ((e == i1) ? p1 : 0.f);

        float* orow = out + (size_t)token * 8;
        *(float4*)(orow)     = make_float4(pr[0], pr[1], pr[2], pr[3]);
        *(float4*)(orow + 4) = make_float4(pr[4], pr[5], pr[6], pr[7]);

        *(float2*)(out + (size_t)ntok * 8 + (size_t)token * 2) =
            make_float2((float)i0, (float)i1);
    }
}

extern "C" void kernel_launch(void* const* d_in, const int* in_sizes, int n_in,
                              void* d_out, int out_size, void* d_ws, size_t ws_size,
                              hipStream_t stream) {
    const float* x       = (const float*)d_in[0];
    const float* noise   = (const float*)d_in[1];
    const float* w_route = (const float*)d_in[2];
    const float* b_route = (const float*)d_in[3];
    const float* w_noise = (const float*)d_in[4];
    const float* b_noise = (const float*)d_in[5];
    float* out = (float*)d_out;

    const int ntok   = in_sizes[0] / D;   // 65536
    const int blocks = ntok / 128;        // 128 tokens per 256-thread block

    hipLaunchKernelGGL(noisy_topk_router_f32, dim3(blocks), dim3(256), 0, stream,
                       x, noise, w_route, b_route, w_noise, b_noise, out, ntok);
}